// Round 2
// 23774.658 us; speedup vs baseline: 1.1484x; 1.1484x over previous
//
#include <hip/hip_runtime.h>

#define TT 8192
#define DD 2048
#define NWG 128
#define RPW 16          // rows of h per workgroup (DD / NWG)
#define NTH 256
#define NREP 8          // replica h-buffers to spread LLC poll hotspot

typedef unsigned long long u64;
#define SIGN2 0x8000000080000000ULL

// ---------------- Phase 1: pre = x @ W1^T + b1  (M=TT, N=DD, K=DD) ----------
#define BM 128
#define BN 128
#define BK 16

__global__ __launch_bounds__(NTH)
void gemm_abt_bias(const float* __restrict__ A, const float* __restrict__ B,
                   const float* __restrict__ bias, float* __restrict__ C,
                   int M, int N, int K) {
  __shared__ float As[BK][BM + 4];
  __shared__ float Bs[BK][BN + 4];
  const int ntile = N / BN;
  const int bn = blockIdx.x % ntile;
  const int bm = blockIdx.x / ntile;
  const int tid = (int)threadIdx.x;
  const int tx = tid & 15;
  const int ty = tid >> 4;

  float acc[8][8];
#pragma unroll
  for (int i = 0; i < 8; ++i)
#pragma unroll
    for (int j = 0; j < 8; ++j) acc[i][j] = 0.f;

  for (int kt = 0; kt < K; kt += BK) {
#pragma unroll
    for (int i = 0; i < 2; ++i) {
      int f = tid + i * 256;
      int row = f >> 2, c4 = f & 3;
      const float4 av = *(const float4*)(A + (size_t)(bm * BM + row) * K + kt + c4 * 4);
      As[c4 * 4 + 0][row] = av.x; As[c4 * 4 + 1][row] = av.y;
      As[c4 * 4 + 2][row] = av.z; As[c4 * 4 + 3][row] = av.w;
      const float4 bv = *(const float4*)(B + (size_t)(bn * BN + row) * K + kt + c4 * 4);
      Bs[c4 * 4 + 0][row] = bv.x; Bs[c4 * 4 + 1][row] = bv.y;
      Bs[c4 * 4 + 2][row] = bv.z; Bs[c4 * 4 + 3][row] = bv.w;
    }
    __syncthreads();
#pragma unroll
    for (int kk = 0; kk < BK; ++kk) {
      float a[8], b[8];
      *(float4*)&a[0] = *(const float4*)&As[kk][ty * 8];
      *(float4*)&a[4] = *(const float4*)&As[kk][ty * 8 + 4];
      *(float4*)&b[0] = *(const float4*)&Bs[kk][tx * 8];
      *(float4*)&b[4] = *(const float4*)&Bs[kk][tx * 8 + 4];
#pragma unroll
      for (int i = 0; i < 8; ++i)
#pragma unroll
        for (int j = 0; j < 8; ++j) acc[i][j] += a[i] * b[j];
    }
    __syncthreads();
  }

  const int col0 = bn * BN + tx * 8;
  const float4 bv0 = *(const float4*)(bias + col0);
  const float4 bv1 = *(const float4*)(bias + col0 + 4);
#pragma unroll
  for (int i = 0; i < 8; ++i) {
    float* crow = C + (size_t)(bm * BM + ty * 8 + i) * N + col0;
    float4 v0 = { acc[i][0] + bv0.x, acc[i][1] + bv0.y, acc[i][2] + bv0.z, acc[i][3] + bv0.w };
    float4 v1 = { acc[i][4] + bv1.x, acc[i][5] + bv1.y, acc[i][6] + bv1.z, acc[i][7] + bv1.w };
    *(float4*)(crow) = v0;
    *(float4*)(crow + 4) = v1;
  }
}

// ---------------- Phase 2: persistent recurrent kernel ----------------------
__device__ __forceinline__ float wave_sum(float v) {
#pragma unroll
  for (int off = 32; off > 0; off >>= 1) v += __shfl_down(v, off, 64);
  return v;
}

__device__ __forceinline__ u64 aload(const u64* p) {
  return __hip_atomic_load(p, __ATOMIC_RELAXED, __HIP_MEMORY_SCOPE_AGENT);
}
__device__ __forceinline__ void astore(u64* p, u64 v) {
  __hip_atomic_store(p, v, __ATOMIC_RELAXED, __HIP_MEMORY_SCOPE_AGENT);
}

// Sync protocol (relaxed agent-scope ONLY — round-1 post-mortem: any
// sub-agent-scope cache path can serve period-4 tag-valid stale data;
// parity tags in the sign bits of ReLU-nonnegative h; slot = t&1,
// tag = (t>>1)&1):
//  * NREP=8 replica h-buffers, layout [slot][rep][DD floats]. Consumer group
//    g = wg & (NREP-1) polls only replica g -> ~16 WGs/replica, ~32 poll
//    streams per 64B line (4x fewer than the 256-WG/4-rep baseline).
//    Grouping is arbitrary (any assignment correct) - no placement assumption.
//  * GEMV is partitioned so each thread consumes EXACTLY the 32B chunk it
//    polls: thread tid owns k in [8*tid, 8*tid+8) = u64s 4*tid..4*tid+3.
//    W2 for all 16 WG-rows x that k-slice lives in 128 VGPRs. Detection ->
//    FMA immediately, no LDS staging of h, no barrier before compute. One
//    barrier/step (cross-wave partial combine, double-buffered LDS partials).
//  * Producer combine: wave 0 (tid<64, no divergence): c = tid>>3 selects the
//    u64 chunk (rows 2c,2c+1 of this WG), rp = tid&7 selects the replica.
//    Exactly one agent store per combine thread (same as baseline).
//  * ABA/slot-reuse safety (induction): any h_{t+2} chunk in any replica
//    implies its producer detected ALL of h_{t+1} in its replica, which
//    implies every WG stored h_{t+1} (to all replicas), which implies every
//    WG finished its step-t reads. Poll values are consumed from the same
//    registers that passed the tag check (no re-read).
//  * Anti-poison: slot0 = 0x00 (tag 0; first tenant h_2 expects tag 1),
//    slot1 = 0xAA (tag 1; first tenant h_1 expects tag 0).
__global__ void __launch_bounds__(NTH, 1)
recurrent_kernel(const float* __restrict__ h0,
                 const float* __restrict__ W2,
                 const float* __restrict__ b2,
                 const float* __restrict__ pre,
                 const float* __restrict__ Wf,
                 const float* __restrict__ bf,
                 float* __restrict__ out,
                 float* hbuf) {     // 2 * NREP * DD floats
  __shared__ float partial[2][4][RPW];   // [t&1][wave][row]
  __shared__ float hs[DD];               // epilogue only

  const int wg   = (int)blockIdx.x;
  const int tid  = (int)threadIdx.x;
  const int lane = tid & 63;
  const int wave = tid >> 6;
  const int grp  = wg & (NREP - 1);
  const int k0   = 8 * tid;            // this thread's k-slice

  // W2 for all 16 WG rows x my 8 k values: 128 VGPRs, fully unrolled indexing.
  float w2[RPW * 8];
#pragma unroll
  for (int r = 0; r < RPW; ++r) {
    *(float4*)&w2[r * 8]     = *(const float4*)(W2 + (size_t)(wg * RPW + r) * DD + k0);
    *(float4*)&w2[r * 8 + 4] = *(const float4*)(W2 + (size_t)(wg * RPW + r) * DD + k0 + 4);
  }
  // Final-combine constants for wave 0 (c = tid>>3 -> rows 2c,2c+1).
  float b2a = 0.f, b2b = 0.f;
  if (tid < 64) {
    const int c = tid >> 3;
    b2a = b2[wg * RPW + 2 * c];
    b2b = b2[wg * RPW + 2 * c + 1];
  }

  u64* const hbU = (u64*)hbuf;   // u64 index: ((slot*NREP)+rep)*(DD/2) + i

  for (int t = 0; t < TT; ++t) {
    // Prefetch pre pair for the final combine (wave 0), pre-poll.
    float2 p2 = {0.f, 0.f};
    if (tid < 64) p2 = *(const float2*)(pre + (size_t)t * DD + wg * RPW + 2 * (tid >> 3));

    float h[8];
    if (t == 0) {
      const float4 a = *(const float4*)(h0 + k0);
      const float4 b = *(const float4*)(h0 + k0 + 4);
      h[0]=a.x; h[1]=a.y; h[2]=a.z; h[3]=a.w;
      h[4]=b.x; h[5]=b.y; h[6]=b.z; h[7]=b.w;
    } else {
      u64* src = hbU + (size_t)((t & 1) * NREP + grp) * (DD / 2) + 4 * tid;
      const u64 EXP = ((t >> 1) & 1) ? SIGN2 : 0ULL;
      u64 u0, u1, u2, u3;
      for (;;) {
        u0 = aload(src + 0); u1 = aload(src + 1);
        u2 = aload(src + 2); u3 = aload(src + 3);
        if (((((u0 ^ EXP) | (u1 ^ EXP)) | ((u2 ^ EXP) | (u3 ^ EXP))) & SIGN2) == 0ULL)
          break;
        __builtin_amdgcn_s_sleep(1);
      }
      u0 &= ~SIGN2; u1 &= ~SIGN2; u2 &= ~SIGN2; u3 &= ~SIGN2;
      h[0]=__uint_as_float((unsigned)u0); h[1]=__uint_as_float((unsigned)(u0>>32));
      h[2]=__uint_as_float((unsigned)u1); h[3]=__uint_as_float((unsigned)(u1>>32));
      h[4]=__uint_as_float((unsigned)u2); h[5]=__uint_as_float((unsigned)(u2>>32));
      h[6]=__uint_as_float((unsigned)u3); h[7]=__uint_as_float((unsigned)(u3>>32));
    }

    // Straight-from-registers partial GEMV: 16 rows x my 8 k.
    float acc[RPW];
#pragma unroll
    for (int r = 0; r < RPW; ++r) acc[r] = 0.f;
#pragma unroll
    for (int i = 0; i < 8; ++i)
#pragma unroll
      for (int r = 0; r < RPW; ++r) acc[r] += w2[r * 8 + i] * h[i];

#pragma unroll
    for (int r = 0; r < RPW; ++r) acc[r] = wave_sum(acc[r]);

    if (lane == 0) {
#pragma unroll
      for (int r = 0; r < RPW; r += 4) {
        float4 v = { acc[r], acc[r + 1], acc[r + 2], acc[r + 3] };
        *(float4*)&partial[t & 1][wave][r] = v;
      }
    }
    __syncthreads();   // the only barrier per step (partials double-buffered)

    if (tid < 64) {
      const int c = tid >> 3, rp = tid & 7;
      const float* P = &partial[t & 1][0][0];
      const float s0 = P[0*RPW+2*c] + P[1*RPW+2*c] + P[2*RPW+2*c] + P[3*RPW+2*c];
      const float s1 = P[0*RPW+2*c+1] + P[1*RPW+2*c+1] + P[2*RPW+2*c+1] + P[3*RPW+2*c+1];
      const float v0 = fmaxf(p2.x + b2a + s0, 0.f);
      const float v1 = fmaxf(p2.y + b2b + s1, 0.f);
      u64 u = (((u64)__float_as_uint(v1) << 32) | (u64)__float_as_uint(v0)) & ~SIGN2;
      if (((t + 1) >> 1) & 1) u |= SIGN2;
      astore(hbU + (size_t)(((t + 1) & 1) * NREP + rp) * (DD / 2) + wg * 8 + c, u);
    }
  }

  if (wg != 0) return;

  // WG0 epilogue: out = Wf @ h_TT + bf. h_8192: slot 0, rep 0, tag 0.
  {
    u64* src = hbU + 4 * tid;
    u64 u0, u1, u2, u3;
    for (;;) {
      u0 = aload(src + 0); u1 = aload(src + 1);
      u2 = aload(src + 2); u3 = aload(src + 3);
      if ((((u0 | u1) | (u2 | u3)) & SIGN2) == 0ULL) break;
      __builtin_amdgcn_s_sleep(1);
    }
    u64* dst = (u64*)hs + 4 * tid;
    dst[0] = u0; dst[1] = u1; dst[2] = u2; dst[3] = u3;
  }
  __syncthreads();
  float acc = 0.f;
#pragma unroll
  for (int j = 0; j < 8; ++j) {
    const float4 wv = *(const float4*)(Wf + (size_t)wave * DD + j * 256 + 4 * lane);
    const float4 hv = *(const float4*)&hs[j * 256 + 4 * lane];
    acc += wv.x * hv.x + wv.y * hv.y + wv.z * hv.z + wv.w * hv.w;
  }
  acc = wave_sum(acc);
  if (lane == 0) out[wave] = acc + bf[wave];
}

// ---------------- Launch ----------------------------------------------------
extern "C" void kernel_launch(void* const* d_in, const int* in_sizes, int n_in,
                              void* d_out, int out_size, void* d_ws, size_t ws_size,
                              hipStream_t stream) {
  const float* x  = (const float*)d_in[0];
  const float* h0 = (const float*)d_in[1];
  const float* W1 = (const float*)d_in[2];
  const float* b1 = (const float*)d_in[3];
  const float* W2 = (const float*)d_in[4];
  const float* b2 = (const float*)d_in[5];
  const float* Wf = (const float*)d_in[6];
  const float* bf = (const float*)d_in[7];
  float* out = (float*)d_out;

  // Workspace: pre (64 MB) | hbuf (2 slots x NREP x DD floats = 128 KB)
  float* pre  = (float*)d_ws;
  float* hbuf = pre + (size_t)TT * DD;

  // Anti-poison slot init (see kernel comment).
  hipMemsetAsync(hbuf, 0x00, NREP * DD * sizeof(float), stream);              // slot0
  hipMemsetAsync(hbuf + NREP * DD, 0xAA, NREP * DD * sizeof(float), stream);  // slot1

  gemm_abt_bias<<<dim3((TT / BM) * (DD / BN)), dim3(NTH), 0, stream>>>(
      x, W1, b1, pre, TT, DD, DD);
  recurrent_kernel<<<dim3(NWG), dim3(NTH), 0, stream>>>(
      h0, W2, b2, pre, Wf, bf, out, hbuf);
}

// Round 3
// 17780.202 us; speedup vs baseline: 1.5356x; 1.3371x over previous
//
#include <hip/hip_runtime.h>

#define TT 8192
#define DD 2048
#define NWG 128
#define RPW 16          // rows of h per workgroup (DD / NWG)
#define NTH 256
#define NREP 8          // replica h-buffers to spread LLC poll hotspot

typedef unsigned long long u64;
#define SIGN2 0x8000000080000000ULL

// ---------------- Phase 1: pre = x @ W1^T + b1  (M=TT, N=DD, K=DD) ----------
#define BM 128
#define BN 128
#define BK 16

__global__ __launch_bounds__(NTH)
void gemm_abt_bias(const float* __restrict__ A, const float* __restrict__ B,
                   const float* __restrict__ bias, float* __restrict__ C,
                   int M, int N, int K) {
  __shared__ float As[BK][BM + 4];
  __shared__ float Bs[BK][BN + 4];
  const int ntile = N / BN;
  const int bn = blockIdx.x % ntile;
  const int bm = blockIdx.x / ntile;
  const int tid = (int)threadIdx.x;
  const int tx = tid & 15;
  const int ty = tid >> 4;

  float acc[8][8];
#pragma unroll
  for (int i = 0; i < 8; ++i)
#pragma unroll
    for (int j = 0; j < 8; ++j) acc[i][j] = 0.f;

  for (int kt = 0; kt < K; kt += BK) {
#pragma unroll
    for (int i = 0; i < 2; ++i) {
      int f = tid + i * 256;
      int row = f >> 2, c4 = f & 3;
      const float4 av = *(const float4*)(A + (size_t)(bm * BM + row) * K + kt + c4 * 4);
      As[c4 * 4 + 0][row] = av.x; As[c4 * 4 + 1][row] = av.y;
      As[c4 * 4 + 2][row] = av.z; As[c4 * 4 + 3][row] = av.w;
      const float4 bv = *(const float4*)(B + (size_t)(bn * BN + row) * K + kt + c4 * 4);
      Bs[c4 * 4 + 0][row] = bv.x; Bs[c4 * 4 + 1][row] = bv.y;
      Bs[c4 * 4 + 2][row] = bv.z; Bs[c4 * 4 + 3][row] = bv.w;
    }
    __syncthreads();
#pragma unroll
    for (int kk = 0; kk < BK; ++kk) {
      float a[8], b[8];
      *(float4*)&a[0] = *(const float4*)&As[kk][ty * 8];
      *(float4*)&a[4] = *(const float4*)&As[kk][ty * 8 + 4];
      *(float4*)&b[0] = *(const float4*)&Bs[kk][tx * 8];
      *(float4*)&b[4] = *(const float4*)&Bs[kk][tx * 8 + 4];
#pragma unroll
      for (int i = 0; i < 8; ++i)
#pragma unroll
        for (int j = 0; j < 8; ++j) acc[i][j] += a[i] * b[j];
    }
    __syncthreads();
  }

  const int col0 = bn * BN + tx * 8;
  const float4 bv0 = *(const float4*)(bias + col0);
  const float4 bv1 = *(const float4*)(bias + col0 + 4);
#pragma unroll
  for (int i = 0; i < 8; ++i) {
    float* crow = C + (size_t)(bm * BM + ty * 8 + i) * N + col0;
    float4 v0 = { acc[i][0] + bv0.x, acc[i][1] + bv0.y, acc[i][2] + bv0.z, acc[i][3] + bv0.w };
    float4 v1 = { acc[i][4] + bv1.x, acc[i][5] + bv1.y, acc[i][6] + bv1.z, acc[i][7] + bv1.w };
    *(float4*)(crow) = v0;
    *(float4*)(crow + 4) = v1;
  }
}

// ---------------- Phase 2: persistent recurrent kernel ----------------------
__device__ __forceinline__ float wave_sum(float v) {
#pragma unroll
  for (int off = 32; off > 0; off >>= 1) v += __shfl_down(v, off, 64);
  return v;
}

__device__ __forceinline__ u64 aload(const u64* p) {
  return __hip_atomic_load(p, __ATOMIC_RELAXED, __HIP_MEMORY_SCOPE_AGENT);
}
__device__ __forceinline__ void astore(u64* p, u64 v) {
  __hip_atomic_store(p, v, __ATOMIC_RELAXED, __HIP_MEMORY_SCOPE_AGENT);
}

// Sync protocol: unchanged from the verified round-2 kernel (relaxed
// agent-scope only; parity tags in sign bits; slot = t&1, tag = (t>>1)&1;
// NREP=8 replicas; consumer group g = wg&7 polls replica g; thread tid owns
// k [8*tid, 8*tid+8); ABA induction + anti-poison as before).
//
// New in round 3 (chain-compute cuts; protocol untouched):
//  * w2 VGPR pinning: VGPR_Count=100 with w2[128] proved the compiler was
//    rematerializing the loop-invariant W2 loads INSIDE the t-loop (~32
//    L2-latency loads per step on the serial chain). An empty volatile asm
//    with "+v" ties makes the loaded values opaque asm outputs -> must stay
//    resident across the loop.
//  * Butterfly fold reduction (17 shuffles vs 96): lane l's w2 slot j holds
//    row j ^ bitrev4(l&15). Invariant: at every stage, kept slot j = row
//    j^lp summed over a growing lane group; partner's sent slot aligns
//    because flipping lane bit s-1 flips lp bit 4-s. After 6 stages lane l
//    holds the full 64-lane sum of row lp = bitrev4(l&15); lanes 0..15
//    (bijection) write LDS. Cross-wave combine unchanged.
__global__ void __launch_bounds__(NTH, 1)
recurrent_kernel(const float* __restrict__ h0,
                 const float* __restrict__ W2,
                 const float* __restrict__ b2,
                 const float* __restrict__ pre,
                 const float* __restrict__ Wf,
                 const float* __restrict__ bf,
                 float* __restrict__ out,
                 float* hbuf) {     // 2 * NREP * DD floats
  __shared__ float partial[2][4][RPW];   // [t&1][wave][row]
  __shared__ float hs[DD];               // epilogue only

  const int wg   = (int)blockIdx.x;
  const int tid  = (int)threadIdx.x;
  const int lane = tid & 63;
  const int wave = tid >> 6;
  const int grp  = wg & (NREP - 1);
  const int k0   = 8 * tid;            // this thread's k-slice

  // bitrev4 of low lane bits: lane bit0->lp bit3, b1->b2, b2->b1, b3->b0.
  const int lp = ((lane & 1) << 3) | ((lane & 2) << 1) |
                 ((lane & 4) >> 1) | ((lane & 8) >> 3);

  // W2 for all 16 WG rows x my 8 k values, rows permuted per-lane for the
  // fold (slot j = row j ^ lp). 128 VGPRs, pinned below.
  float w2[RPW * 8];
#pragma unroll
  for (int j = 0; j < RPW; ++j) {
    const size_t r = (size_t)(wg * RPW + (j ^ lp));
    *(float4*)&w2[j * 8]     = *(const float4*)(W2 + r * DD + k0);
    *(float4*)&w2[j * 8 + 4] = *(const float4*)(W2 + r * DD + k0 + 4);
  }
  // Pin: make each value an opaque volatile-asm output so the compiler
  // cannot sink/rematerialize the W2 loads into the t-loop.
#pragma unroll
  for (int i = 0; i < RPW * 8; i += 4)
    asm volatile("" : "+v"(w2[i]), "+v"(w2[i + 1]), "+v"(w2[i + 2]), "+v"(w2[i + 3]));

  // Final-combine constants for wave 0 (c = tid>>3 -> rows 2c,2c+1).
  float b2a = 0.f, b2b = 0.f;
  if (tid < 64) {
    const int c = tid >> 3;
    b2a = b2[wg * RPW + 2 * c];
    b2b = b2[wg * RPW + 2 * c + 1];
  }

  u64* const hbU = (u64*)hbuf;   // u64 index: ((slot*NREP)+rep)*(DD/2) + i

  for (int t = 0; t < TT; ++t) {
    // Prefetch pre pair for the final combine (wave 0), pre-poll.
    float2 p2 = {0.f, 0.f};
    if (tid < 64) p2 = *(const float2*)(pre + (size_t)t * DD + wg * RPW + 2 * (tid >> 3));

    float h[8];
    if (t == 0) {
      const float4 a = *(const float4*)(h0 + k0);
      const float4 b = *(const float4*)(h0 + k0 + 4);
      h[0]=a.x; h[1]=a.y; h[2]=a.z; h[3]=a.w;
      h[4]=b.x; h[5]=b.y; h[6]=b.z; h[7]=b.w;
    } else {
      u64* src = hbU + (size_t)((t & 1) * NREP + grp) * (DD / 2) + 4 * tid;
      const u64 EXP = ((t >> 1) & 1) ? SIGN2 : 0ULL;
      u64 u0, u1, u2, u3;
      for (;;) {
        u0 = aload(src + 0); u1 = aload(src + 1);
        u2 = aload(src + 2); u3 = aload(src + 3);
        if (((((u0 ^ EXP) | (u1 ^ EXP)) | ((u2 ^ EXP) | (u3 ^ EXP))) & SIGN2) == 0ULL)
          break;
        __builtin_amdgcn_s_sleep(1);
      }
      u0 &= ~SIGN2; u1 &= ~SIGN2; u2 &= ~SIGN2; u3 &= ~SIGN2;
      h[0]=__uint_as_float((unsigned)u0); h[1]=__uint_as_float((unsigned)(u0>>32));
      h[2]=__uint_as_float((unsigned)u1); h[3]=__uint_as_float((unsigned)(u1>>32));
      h[4]=__uint_as_float((unsigned)u2); h[5]=__uint_as_float((unsigned)(u2>>32));
      h[6]=__uint_as_float((unsigned)u3); h[7]=__uint_as_float((unsigned)(u3>>32));
    }

    // Straight-from-registers partial GEMV: 16 (permuted) rows x my 8 k.
    float acc[RPW];
#pragma unroll
    for (int r = 0; r < RPW; ++r) acc[r] = 0.f;
#pragma unroll
    for (int i = 0; i < 8; ++i)
#pragma unroll
      for (int r = 0; r < RPW; ++r) acc[r] += w2[r * 8 + i] * h[i];

    // Butterfly fold: 16 rows x 64 lanes in 17 shuffles + 17 adds.
#pragma unroll
    for (int j = 0; j < 8; ++j) acc[j] += __shfl_xor(acc[8 + j], 1, 64);
#pragma unroll
    for (int j = 0; j < 4; ++j) acc[j] += __shfl_xor(acc[4 + j], 2, 64);
#pragma unroll
    for (int j = 0; j < 2; ++j) acc[j] += __shfl_xor(acc[2 + j], 4, 64);
    acc[0] += __shfl_xor(acc[1], 8, 64);
    acc[0] += __shfl_xor(acc[0], 16, 64);
    acc[0] += __shfl_xor(acc[0], 32, 64);

    if (lane < 16) partial[t & 1][wave][lp] = acc[0];
    __syncthreads();   // the only barrier per step (partials double-buffered)

    if (tid < 64) {
      const int c = tid >> 3, rp = tid & 7;
      const float* P = &partial[t & 1][0][0];
      const float s0 = P[0*RPW+2*c] + P[1*RPW+2*c] + P[2*RPW+2*c] + P[3*RPW+2*c];
      const float s1 = P[0*RPW+2*c+1] + P[1*RPW+2*c+1] + P[2*RPW+2*c+1] + P[3*RPW+2*c+1];
      const float v0 = fmaxf(p2.x + b2a + s0, 0.f);
      const float v1 = fmaxf(p2.y + b2b + s1, 0.f);
      u64 u = (((u64)__float_as_uint(v1) << 32) | (u64)__float_as_uint(v0)) & ~SIGN2;
      if (((t + 1) >> 1) & 1) u |= SIGN2;
      astore(hbU + (size_t)(((t + 1) & 1) * NREP + rp) * (DD / 2) + wg * 8 + c, u);
    }
  }

  if (wg != 0) return;

  // WG0 epilogue: out = Wf @ h_TT + bf. h_8192: slot 0, rep 0, tag 0.
  {
    u64* src = hbU + 4 * tid;
    u64 u0, u1, u2, u3;
    for (;;) {
      u0 = aload(src + 0); u1 = aload(src + 1);
      u2 = aload(src + 2); u3 = aload(src + 3);
      if ((((u0 | u1) | (u2 | u3)) & SIGN2) == 0ULL) break;
      __builtin_amdgcn_s_sleep(1);
    }
    u64* dst = (u64*)hs + 4 * tid;
    dst[0] = u0; dst[1] = u1; dst[2] = u2; dst[3] = u3;
  }
  __syncthreads();
  float acc = 0.f;
#pragma unroll
  for (int j = 0; j < 8; ++j) {
    const float4 wv = *(const float4*)(Wf + (size_t)wave * DD + j * 256 + 4 * lane);
    const float4 hv = *(const float4*)&hs[j * 256 + 4 * lane];
    acc += wv.x * hv.x + wv.y * hv.y + wv.z * hv.z + wv.w * hv.w;
  }
  acc = wave_sum(acc);
  if (lane == 0) out[wave] = acc + bf[wave];
}

// ---------------- Launch ----------------------------------------------------
extern "C" void kernel_launch(void* const* d_in, const int* in_sizes, int n_in,
                              void* d_out, int out_size, void* d_ws, size_t ws_size,
                              hipStream_t stream) {
  const float* x  = (const float*)d_in[0];
  const float* h0 = (const float*)d_in[1];
  const float* W1 = (const float*)d_in[2];
  const float* b1 = (const float*)d_in[3];
  const float* W2 = (const float*)d_in[4];
  const float* b2 = (const float*)d_in[5];
  const float* Wf = (const float*)d_in[6];
  const float* bf = (const float*)d_in[7];
  float* out = (float*)d_out;

  // Workspace: pre (64 MB) | hbuf (2 slots x NREP x DD floats = 128 KB)
  float* pre  = (float*)d_ws;
  float* hbuf = pre + (size_t)TT * DD;

  // Anti-poison slot init (see kernel comment).
  hipMemsetAsync(hbuf, 0x00, NREP * DD * sizeof(float), stream);              // slot0
  hipMemsetAsync(hbuf + NREP * DD, 0xAA, NREP * DD * sizeof(float), stream);  // slot1

  gemm_abt_bias<<<dim3((TT / BM) * (DD / BN)), dim3(NTH), 0, stream>>>(
      x, W1, b1, pre, TT, DD, DD);
  recurrent_kernel<<<dim3(NWG), dim3(NTH), 0, stream>>>(
      h0, W2, b2, pre, Wf, bf, out, hbuf);
}